// Round 1
// baseline (2903.173 us; speedup 1.0000x reference)
//
#include <hip/hip_runtime.h>
#include <cstdint>
#include <cstddef>

#define IN_DIM 512
#define HID 2048
#define TOPK 50

// ---------------------------------------------------------------------------
// K0: transpose W_dec (512 x 2048) -> W_dec_T (2048 x 512) in workspace
// ---------------------------------------------------------------------------
__global__ __launch_bounds__(256) void transpose_wdec_kernel(
    const float* __restrict__ Wd, float* __restrict__ WdT)
{
  __shared__ float tile[32][33];
  const int bx = blockIdx.x & 63;   // h tile: 2048/32 = 64
  const int by = blockIdx.x >> 6;   // d tile: 512/32  = 16
  const int tx = threadIdx.x & 31;
  const int ty = threadIdx.x >> 5;  // 0..7
#pragma unroll
  for (int i = 0; i < 4; ++i) {
    const int d = by * 32 + ty + i * 8;
    const int h = bx * 32 + tx;
    tile[ty + i * 8][tx] = Wd[(size_t)d * HID + h];
  }
  __syncthreads();
#pragma unroll
  for (int i = 0; i < 4; ++i) {
    const int h = bx * 32 + ty + i * 8;
    const int d = by * 32 + tx;
    WdT[(size_t)h * IN_DIM + d] = tile[tx][ty + i * 8];
  }
}

// ---------------------------------------------------------------------------
// K1: z = (x - b_dec - pre_bias) @ W_enc^T + b_enc   (fp32 tiled GEMM)
// M x 512 @ (2048 x 512)^T -> M x 2048
// 128x128 block tile, BK=16, 256 threads, 8x8 per-thread microtile
// ---------------------------------------------------------------------------
#define BM 128
#define BN 128
#define BK 16

__global__ __launch_bounds__(256) void enc_gemm_kernel(
    const float* __restrict__ x, const float* __restrict__ We,
    const float* __restrict__ be, const float* __restrict__ bd,
    const float* __restrict__ pb, float* __restrict__ z, int M)
{
  __shared__ __align__(16) float sA[BK][BM + 4];
  __shared__ __align__(16) float sB[BK][BN + 4];
  __shared__ float sBias[IN_DIM];

  const int tid = threadIdx.x;
  const int tn = blockIdx.x & 15;   // HID / BN = 16
  const int tm = blockIdx.x >> 4;
  const int row0 = tm * BM;
  const int col0 = tn * BN;

  for (int i = tid; i < IN_DIM; i += 256) sBias[i] = bd[i] + pb[i];
  __syncthreads();

  float acc[8][8];
#pragma unroll
  for (int i = 0; i < 8; ++i)
#pragma unroll
    for (int j = 0; j < 8; ++j) acc[i][j] = 0.f;

  const int tx = tid & 15;   // n direction
  const int ty = tid >> 4;   // m direction

  for (int k0 = 0; k0 < IN_DIM; k0 += BK) {
    // stage A (with xc subtraction) and B into LDS, [k][m] layout
#pragma unroll
    for (int r = 0; r < 2; ++r) {
      const int i = tid + r * 256;       // 0..511
      const int arow = i >> 2;           // 0..127
      const int kq = (i & 3) << 2;       // 0,4,8,12
      float4 va = *(const float4*)(x + (size_t)(row0 + arow) * IN_DIM + k0 + kq);
      va.x -= sBias[k0 + kq + 0];
      va.y -= sBias[k0 + kq + 1];
      va.z -= sBias[k0 + kq + 2];
      va.w -= sBias[k0 + kq + 3];
      sA[kq + 0][arow] = va.x;
      sA[kq + 1][arow] = va.y;
      sA[kq + 2][arow] = va.z;
      sA[kq + 3][arow] = va.w;
      float4 vb = *(const float4*)(We + (size_t)(col0 + arow) * IN_DIM + k0 + kq);
      sB[kq + 0][arow] = vb.x;
      sB[kq + 1][arow] = vb.y;
      sB[kq + 2][arow] = vb.z;
      sB[kq + 3][arow] = vb.w;
    }
    __syncthreads();

#pragma unroll
    for (int kk = 0; kk < BK; ++kk) {
      float a[8], b[8];
      *(float4*)(a)     = *(const float4*)&sA[kk][ty * 8];
      *(float4*)(a + 4) = *(const float4*)&sA[kk][ty * 8 + 4];
      *(float4*)(b)     = *(const float4*)&sB[kk][tx * 8];
      *(float4*)(b + 4) = *(const float4*)&sB[kk][tx * 8 + 4];
#pragma unroll
      for (int i2 = 0; i2 < 8; ++i2)
#pragma unroll
        for (int j2 = 0; j2 < 8; ++j2) acc[i2][j2] += a[i2] * b[j2];
    }
    __syncthreads();
  }

  // epilogue: + b_enc, store
#pragma unroll
  for (int i = 0; i < 8; ++i) {
    const size_t r = (size_t)(row0 + ty * 8 + i);
    float* zp = z + r * HID + col0 + tx * 8;
    float4 o0, o1;
    o0.x = acc[i][0] + be[col0 + tx * 8 + 0];
    o0.y = acc[i][1] + be[col0 + tx * 8 + 1];
    o0.z = acc[i][2] + be[col0 + tx * 8 + 2];
    o0.w = acc[i][3] + be[col0 + tx * 8 + 3];
    o1.x = acc[i][4] + be[col0 + tx * 8 + 4];
    o1.y = acc[i][5] + be[col0 + tx * 8 + 5];
    o1.z = acc[i][6] + be[col0 + tx * 8 + 6];
    o1.w = acc[i][7] + be[col0 + tx * 8 + 7];
    *(float4*)(zp)     = o0;
    *(float4*)(zp + 4) = o1;
  }
}

// ---------------------------------------------------------------------------
// K2: per-row exact 50th-largest threshold (binary search on sortable uint),
// zero entries below threshold in place. One wave (64 lanes) per row.
// ---------------------------------------------------------------------------
__global__ __launch_bounds__(256) void topk_kernel(float* __restrict__ z, int M)
{
  const int row = blockIdx.x * 4 + (threadIdx.x >> 6);
  const int lane = threadIdx.x & 63;
  float* zr = z + (size_t)row * HID;

  float v[32];
  unsigned u[32];
#pragma unroll
  for (int j = 0; j < 32; ++j) {
    v[j] = zr[lane + 64 * j];
    const unsigned b = __float_as_uint(v[j]);
    u[j] = (b & 0x80000000u) ? ~b : (b | 0x80000000u);  // order-preserving map
  }

  // find largest t with |{u >= t}| >= TOPK  ->  t == code of 50th-largest z
  unsigned lo = 0u, hi = 0xFFFFFFFFu;
  while (hi - lo > 1u) {
    const unsigned mid = lo + ((hi - lo) >> 1);
    int c = 0;
#pragma unroll
    for (int j = 0; j < 32; ++j) c += (u[j] >= mid) ? 1 : 0;
#pragma unroll
    for (int s = 32; s > 0; s >>= 1) c += __shfl_xor(c, s, 64);
    if (c >= TOPK) lo = mid; else hi = mid;
  }

#pragma unroll
  for (int j = 0; j < 32; ++j)
    zr[lane + 64 * j] = (u[j] >= lo) ? v[j] : 0.0f;
}

// ---------------------------------------------------------------------------
// K3: recon[n,:] = sum_h z_sparse[n,h] * W_dec_T[h,:] + b_dec
// One wave per row; ballot-scan nonzeros, shuffle-broadcast (h, z).
// ---------------------------------------------------------------------------
__global__ __launch_bounds__(256) void decode_kernel(
    const float* __restrict__ z, const float* __restrict__ WdT,
    const float* __restrict__ bd, float* __restrict__ recon, int M)
{
  const int row = blockIdx.x * 4 + (threadIdx.x >> 6);
  const int lane = threadIdx.x & 63;
  const float* zr = z + (size_t)row * HID;

  float acc[8];
#pragma unroll
  for (int t = 0; t < 8; ++t) acc[t] = bd[lane + 64 * t];

  for (int j = 0; j < 32; ++j) {
    const float val = zr[lane + 64 * j];
    unsigned long long mask = __ballot(val != 0.0f);
    while (mask) {
      const int b = __ffsll(mask) - 1;
      mask &= mask - 1;
      const float zv = __shfl(val, b, 64);
      const float* wrow = WdT + (size_t)(j * 64 + b) * IN_DIM;
#pragma unroll
      for (int t = 0; t < 8; ++t) acc[t] += zv * wrow[lane + 64 * t];
    }
  }

  float* rr = recon + (size_t)row * IN_DIM;
#pragma unroll
  for (int t = 0; t < 8; ++t) rr[lane + 64 * t] = acc[t];
}

// ---------------------------------------------------------------------------
extern "C" void kernel_launch(void* const* d_in, const int* in_sizes, int n_in,
                              void* d_out, int out_size, void* d_ws, size_t ws_size,
                              hipStream_t stream)
{
  const float* x   = (const float*)d_in[0];
  const float* We  = (const float*)d_in[1];
  const float* be  = (const float*)d_in[2];
  const float* Wd  = (const float*)d_in[3];
  const float* bd  = (const float*)d_in[4];
  const float* pb  = (const float*)d_in[5];

  const int M = in_sizes[0] / IN_DIM;   // 65536

  float* recon = (float*)d_out;                       // M x 512
  float* zs    = (float*)d_out + (size_t)M * IN_DIM;  // M x 2048 (also used as z scratch)
  float* WdT   = (float*)d_ws;                        // 2048 x 512 = 4 MB

  transpose_wdec_kernel<<<1024, 256, 0, stream>>>(Wd, WdT);
  enc_gemm_kernel<<<(M / BM) * (HID / BN), 256, 0, stream>>>(x, We, be, bd, pb, zs, M);
  topk_kernel<<<M / 4, 256, 0, stream>>>(zs, M);
  decode_kernel<<<M / 4, 256, 0, stream>>>(zs, WdT, bd, recon, M);
}

// Round 2
// 2831.552 us; speedup vs baseline: 1.0253x; 1.0253x over previous
//
#include <hip/hip_runtime.h>
#include <cstdint>
#include <cstddef>

#define IN_DIM 512
#define HID 2048
#define TOPK 50

// ---------------------------------------------------------------------------
// K0: transpose W_dec (512 x 2048) -> W_dec_T (2048 x 512) in workspace
// ---------------------------------------------------------------------------
__global__ __launch_bounds__(256) void transpose_wdec_kernel(
    const float* __restrict__ Wd, float* __restrict__ WdT)
{
  __shared__ float tile[32][33];
  const int bx = blockIdx.x & 63;   // h tile: 2048/32 = 64
  const int by = blockIdx.x >> 6;   // d tile: 512/32  = 16
  const int tx = threadIdx.x & 31;
  const int ty = threadIdx.x >> 5;  // 0..7
#pragma unroll
  for (int i = 0; i < 4; ++i) {
    const int d = by * 32 + ty + i * 8;
    const int h = bx * 32 + tx;
    tile[ty + i * 8][tx] = Wd[(size_t)d * HID + h];
  }
  __syncthreads();
#pragma unroll
  for (int i = 0; i < 4; ++i) {
    const int h = bx * 32 + ty + i * 8;
    const int d = by * 32 + tx;
    WdT[(size_t)h * IN_DIM + d] = tile[tx][ty + i * 8];
  }
}

// ---------------------------------------------------------------------------
// K1: z = (x - b_dec - pre_bias) @ W_enc^T + b_enc   (fp32 tiled GEMM)
// 128x128 block tile, BK=16, 256 threads, 8x8 per-thread microtile.
// LDS layout: row stride 146 floats + column swizzle c -> c + (c>>5)*4
//   reads:  16 chunks of 8 floats land 2-way across banks (free, m136)
//   writes: 4 staged rows land on bank offsets {0,8,16,24} -> 2-way (free)
// ---------------------------------------------------------------------------
#define BM 128
#define BN 128
#define BK 16
#define SROW 146

__device__ __forceinline__ int swz(int c) { return c + ((c >> 5) << 2); }

__global__ __launch_bounds__(256) void enc_gemm_kernel(
    const float* __restrict__ x, const float* __restrict__ We,
    const float* __restrict__ be, const float* __restrict__ bd,
    const float* __restrict__ pb, float* __restrict__ z, int M)
{
  __shared__ __align__(16) float sA[BK * SROW];
  __shared__ __align__(16) float sB[BK * SROW];
  __shared__ float sBias[IN_DIM];

  const int tid = threadIdx.x;
  const int tn = blockIdx.x & 15;   // HID / BN = 16
  const int tm = blockIdx.x >> 4;
  const int row0 = tm * BM;
  const int col0 = tn * BN;

  for (int i = tid; i < IN_DIM; i += 256) sBias[i] = bd[i] + pb[i];
  __syncthreads();

  float acc[8][8];
#pragma unroll
  for (int i = 0; i < 8; ++i)
#pragma unroll
    for (int j = 0; j < 8; ++j) acc[i][j] = 0.f;

  const int tx = tid & 15;   // n direction
  const int ty = tid >> 4;   // m direction
  const int aoff = swz(ty * 8);   // 8-float chunks never cross a 32 boundary
  const int boff = swz(tx * 8);

  for (int k0 = 0; k0 < IN_DIM; k0 += BK) {
#pragma unroll
    for (int r = 0; r < 2; ++r) {
      const int i2 = tid + r * 256;      // 0..511
      const int arow = i2 >> 2;          // 0..127
      const int kq = (i2 & 3) << 2;      // 0,4,8,12
      const int sc = swz(arow);
      float4 va = *(const float4*)(x + (size_t)(row0 + arow) * IN_DIM + k0 + kq);
      va.x -= sBias[k0 + kq + 0];
      va.y -= sBias[k0 + kq + 1];
      va.z -= sBias[k0 + kq + 2];
      va.w -= sBias[k0 + kq + 3];
      sA[(kq + 0) * SROW + sc] = va.x;
      sA[(kq + 1) * SROW + sc] = va.y;
      sA[(kq + 2) * SROW + sc] = va.z;
      sA[(kq + 3) * SROW + sc] = va.w;
      float4 vb = *(const float4*)(We + (size_t)(col0 + arow) * IN_DIM + k0 + kq);
      sB[(kq + 0) * SROW + sc] = vb.x;
      sB[(kq + 1) * SROW + sc] = vb.y;
      sB[(kq + 2) * SROW + sc] = vb.z;
      sB[(kq + 3) * SROW + sc] = vb.w;
    }
    __syncthreads();

#pragma unroll
    for (int kk = 0; kk < BK; ++kk) {
      float a[8], b[8];
      *(float4*)(a)     = *(const float4*)&sA[kk * SROW + aoff];
      *(float4*)(a + 4) = *(const float4*)&sA[kk * SROW + aoff + 4];
      *(float4*)(b)     = *(const float4*)&sB[kk * SROW + boff];
      *(float4*)(b + 4) = *(const float4*)&sB[kk * SROW + boff + 4];
#pragma unroll
      for (int i2 = 0; i2 < 8; ++i2)
#pragma unroll
        for (int j2 = 0; j2 < 8; ++j2) acc[i2][j2] += a[i2] * b[j2];
    }
    __syncthreads();
  }

#pragma unroll
  for (int i = 0; i < 8; ++i) {
    const size_t r = (size_t)(row0 + ty * 8 + i);
    float* zp = z + r * HID + col0 + tx * 8;
    float4 o0, o1;
    o0.x = acc[i][0] + be[col0 + tx * 8 + 0];
    o0.y = acc[i][1] + be[col0 + tx * 8 + 1];
    o0.z = acc[i][2] + be[col0 + tx * 8 + 2];
    o0.w = acc[i][3] + be[col0 + tx * 8 + 3];
    o1.x = acc[i][4] + be[col0 + tx * 8 + 4];
    o1.y = acc[i][5] + be[col0 + tx * 8 + 5];
    o1.z = acc[i][6] + be[col0 + tx * 8 + 6];
    o1.w = acc[i][7] + be[col0 + tx * 8 + 7];
    *(float4*)(zp)     = o0;
    *(float4*)(zp + 4) = o1;
  }
}

// ---------------------------------------------------------------------------
// K2 (fused): per-row exact 50th-largest threshold (binary search on
// sign-flipped float codes), in-place sparsification of z, ballot-compaction
// of surviving (h, val) pairs into LDS, then decode with 8 independent
// accumulators and dwordx4 W_dec_T gathers. One wave per row.
// ---------------------------------------------------------------------------
__global__ __launch_bounds__(256) void topk_decode_kernel(
    float* __restrict__ z, const float* __restrict__ WdT,
    const float* __restrict__ bd, float* __restrict__ recon, int M)
{
  __shared__ float2 s_pair[4][64];
  const int w = threadIdx.x >> 6;
  const int lane = threadIdx.x & 63;
  const int row = blockIdx.x * 4 + w;
  float* zr = z + (size_t)row * HID;

  // vectorized row load: lane covers h = j2*256 + lane*4 + c  (j = j2*4+c)
  float4 v4[8];
  float v[32];
  unsigned u[32];
#pragma unroll
  for (int j2 = 0; j2 < 8; ++j2) {
    v4[j2] = *(const float4*)(zr + j2 * 256 + lane * 4);
    v[j2 * 4 + 0] = v4[j2].x;
    v[j2 * 4 + 1] = v4[j2].y;
    v[j2 * 4 + 2] = v4[j2].z;
    v[j2 * 4 + 3] = v4[j2].w;
  }
#pragma unroll
  for (int j = 0; j < 32; ++j) {
    const unsigned b = __float_as_uint(v[j]);
    u[j] = (b & 0x80000000u) ? ~b : (b | 0x80000000u);  // order-preserving map
  }

  // largest t with |{u >= t}| >= TOPK  ->  t == code of 50th-largest z
  unsigned lo = 0u, hi = 0xFFFFFFFFu;
  while (hi - lo > 1u) {
    const unsigned mid = lo + ((hi - lo) >> 1);
    int c = 0;
#pragma unroll
    for (int j = 0; j < 32; ++j) c += (u[j] >= mid) ? 1 : 0;
#pragma unroll
    for (int s = 32; s > 0; s >>= 1) c += __shfl_xor(c, s, 64);
    if (c >= TOPK) lo = mid; else hi = mid;
  }

  // sparsify in place (vectorized store)
#pragma unroll
  for (int j2 = 0; j2 < 8; ++j2) {
    float4 o;
    o.x = (u[j2 * 4 + 0] >= lo) ? v4[j2].x : 0.0f;
    o.y = (u[j2 * 4 + 1] >= lo) ? v4[j2].y : 0.0f;
    o.z = (u[j2 * 4 + 2] >= lo) ? v4[j2].z : 0.0f;
    o.w = (u[j2 * 4 + 3] >= lo) ? v4[j2].w : 0.0f;
    *(float4*)(zr + j2 * 256 + lane * 4) = o;
  }

  // ballot-compact (h, val) pairs into LDS (wave-local, no barrier needed)
  s_pair[w][lane] = make_float2(0.0f, __int_as_float(0));
  int base = 0;
#pragma unroll
  for (int j = 0; j < 32; ++j) {
    const bool pass = (u[j] >= lo);
    const unsigned long long mask = __ballot(pass);
    if (pass) {
      const int pos = base + __popcll(mask & ((1ull << lane) - 1ull));
      if (pos < 64) {
        const int h = (j >> 2) * 256 + lane * 4 + (j & 3);
        s_pair[w][pos] = make_float2(v[j], __int_as_float(h));
      }
    }
    base += __popcll(mask);
  }
  const int cnt = (base < 64) ? base : 64;

  // decode: recon[row, lane*8 .. lane*8+7]
  float acc[8];
  {
    float4 b0 = *(const float4*)(bd + lane * 8);
    float4 b1 = *(const float4*)(bd + lane * 8 + 4);
    acc[0] = b0.x; acc[1] = b0.y; acc[2] = b0.z; acc[3] = b0.w;
    acc[4] = b1.x; acc[5] = b1.y; acc[6] = b1.z; acc[7] = b1.w;
  }
  for (int i = 0; i < cnt; ++i) {
    const float2 p = s_pair[w][i];          // uniform -> LDS broadcast
    const float zv = p.x;
    const int h = __float_as_int(p.y);
    const float* wr = WdT + (size_t)h * IN_DIM + lane * 8;
    const float4 w0 = *(const float4*)wr;
    const float4 w1 = *(const float4*)(wr + 4);
    acc[0] += zv * w0.x; acc[1] += zv * w0.y;
    acc[2] += zv * w0.z; acc[3] += zv * w0.w;
    acc[4] += zv * w1.x; acc[5] += zv * w1.y;
    acc[6] += zv * w1.z; acc[7] += zv * w1.w;
  }

  float* rr = recon + (size_t)row * IN_DIM + lane * 8;
  float4 o0, o1;
  o0.x = acc[0]; o0.y = acc[1]; o0.z = acc[2]; o0.w = acc[3];
  o1.x = acc[4]; o1.y = acc[5]; o1.z = acc[6]; o1.w = acc[7];
  *(float4*)(rr)     = o0;
  *(float4*)(rr + 4) = o1;
}

// ---------------------------------------------------------------------------
extern "C" void kernel_launch(void* const* d_in, const int* in_sizes, int n_in,
                              void* d_out, int out_size, void* d_ws, size_t ws_size,
                              hipStream_t stream)
{
  const float* x   = (const float*)d_in[0];
  const float* We  = (const float*)d_in[1];
  const float* be  = (const float*)d_in[2];
  const float* Wd  = (const float*)d_in[3];
  const float* bd  = (const float*)d_in[4];
  const float* pb  = (const float*)d_in[5];

  const int M = in_sizes[0] / IN_DIM;   // 65536

  float* recon = (float*)d_out;                       // M x 512
  float* zs    = (float*)d_out + (size_t)M * IN_DIM;  // M x 2048 (z -> z_sparse)
  float* WdT   = (float*)d_ws;                        // 2048 x 512 = 4 MB

  transpose_wdec_kernel<<<1024, 256, 0, stream>>>(Wd, WdT);
  enc_gemm_kernel<<<(M / BM) * (HID / BN), 256, 0, stream>>>(x, We, be, bd, pb, zs, M);
  topk_decode_kernel<<<M / 4, 256, 0, stream>>>(zs, WdT, bd, recon, M);
}

// Round 3
// 2271.690 us; speedup vs baseline: 1.2780x; 1.2465x over previous
//
#include <hip/hip_runtime.h>
#include <cstdint>
#include <cstddef>

#define IN_DIM 512
#define HID 2048
#define TOPK 50
#define MARGIN 4e-5f

typedef __attribute__((ext_vector_type(8))) short short8;
typedef __attribute__((ext_vector_type(4))) float f32x4;

__device__ __forceinline__ unsigned short f2bf(float f) {
  unsigned b = __float_as_uint(f);
  b += 0x7fffu + ((b >> 16) & 1u);          // round-to-nearest-even
  return (unsigned short)(b >> 16);
}
__device__ __forceinline__ float bf2f(unsigned short u) {
  return __uint_as_float(((unsigned)u) << 16);
}
__device__ __forceinline__ unsigned f2code(float f) {
  const unsigned b = __float_as_uint(f);
  return (b & 0x80000000u) ? ~b : (b | 0x80000000u);   // order-preserving
}
__device__ __forceinline__ float code2f(unsigned t) {
  return __uint_as_float((t & 0x80000000u) ? (t & 0x7fffffffu) : ~t);
}
__device__ __forceinline__ void dma16(const void* g, void* l) {
  __builtin_amdgcn_global_load_lds(
      (const __attribute__((address_space(1))) void*)g,
      (__attribute__((address_space(3))) void*)l, 16, 0, 0);
}

// ---------------------------------------------------------------------------
// K0: transpose W_dec (512 x 2048) -> W_dec_T (2048 x 512)
// ---------------------------------------------------------------------------
__global__ __launch_bounds__(256) void transpose_wdec_kernel(
    const float* __restrict__ Wd, float* __restrict__ WdT)
{
  __shared__ float tile[32][33];
  const int bx = blockIdx.x & 63;
  const int by = blockIdx.x >> 6;
  const int tx = threadIdx.x & 31;
  const int ty = threadIdx.x >> 5;
#pragma unroll
  for (int i = 0; i < 4; ++i)
    tile[ty + i * 8][tx] = Wd[(size_t)(by * 32 + ty + i * 8) * HID + bx * 32 + tx];
  __syncthreads();
#pragma unroll
  for (int i = 0; i < 4; ++i)
    WdT[(size_t)(bx * 32 + ty + i * 8) * IN_DIM + by * 32 + tx] = tile[tx][ty + i * 8];
}

// ---------------------------------------------------------------------------
// K1a: split W_enc (2048x512 fp32) -> WeHi, WeLo (bf16 as ushort)
// ---------------------------------------------------------------------------
__global__ __launch_bounds__(256) void split_we_kernel(
    const float* __restrict__ We, unsigned short* __restrict__ wh,
    unsigned short* __restrict__ wl)
{
  const int i4 = blockIdx.x * 256 + threadIdx.x;   // HID*IN_DIM/4 total
  const float4 v = ((const float4*)We)[i4];
  ushort4 h, l;
  h.x = f2bf(v.x); l.x = f2bf(v.x - bf2f(h.x));
  h.y = f2bf(v.y); l.y = f2bf(v.y - bf2f(h.y));
  h.z = f2bf(v.z); l.z = f2bf(v.z - bf2f(h.z));
  h.w = f2bf(v.w); l.w = f2bf(v.w - bf2f(h.w));
  ((ushort4*)wh)[i4] = h;
  ((ushort4*)wl)[i4] = l;
}

// ---------------------------------------------------------------------------
// K1b: xc = x - (b_dec + pre_bias); split -> xcHi, xcLo (stored in recon area)
// ---------------------------------------------------------------------------
__global__ __launch_bounds__(256) void split_x_kernel(
    const float* __restrict__ x, const float* __restrict__ bd,
    const float* __restrict__ pb, unsigned short* __restrict__ xh,
    unsigned short* __restrict__ xl)
{
  const int i4 = blockIdx.x * 256 + threadIdx.x;   // M*IN_DIM/4 total
  const int k4 = (i4 & 127) * 4;
  const float4 v = ((const float4*)x)[i4];
  const float4 b = *(const float4*)(bd + k4);
  const float4 p = *(const float4*)(pb + k4);
  float c0 = v.x - (b.x + p.x);
  float c1 = v.y - (b.y + p.y);
  float c2 = v.z - (b.z + p.z);
  float c3 = v.w - (b.w + p.w);
  ushort4 h, l;
  h.x = f2bf(c0); l.x = f2bf(c0 - bf2f(h.x));
  h.y = f2bf(c1); l.y = f2bf(c1 - bf2f(h.y));
  h.z = f2bf(c2); l.z = f2bf(c2 - bf2f(h.z));
  h.w = f2bf(c3); l.w = f2bf(c3 - bf2f(h.w));
  ((ushort4*)xh)[i4] = h;
  ((ushort4*)xl)[i4] = l;
}

// ---------------------------------------------------------------------------
// K2: z = xc @ We^T + be  via bf16x3 MFMA (hi*hi + hi*lo + lo*hi).
// 128x128 tile, BK=32, 4 waves in 2x2 grid, wave tile 64x64 = 4x4 MFMA tiles.
// All operands DMA'd to LDS via global_load_lds width=16 (m97 structure).
// ---------------------------------------------------------------------------
__global__ __launch_bounds__(256) void enc_gemm_mfma_kernel(
    const unsigned short* __restrict__ xh, const unsigned short* __restrict__ xl,
    const unsigned short* __restrict__ wh, const unsigned short* __restrict__ wl,
    const float* __restrict__ be, float* __restrict__ z)
{
  __shared__ __align__(16) unsigned short sAh[128 * 32];
  __shared__ __align__(16) unsigned short sAl[128 * 32];
  __shared__ __align__(16) unsigned short sBh[128 * 32];
  __shared__ __align__(16) unsigned short sBl[128 * 32];

  const int tid = threadIdx.x;
  const int lane = tid & 63, wv = tid >> 6;
  const int wm = wv & 1, wn = wv >> 1;
  const size_t row0 = (size_t)(blockIdx.x >> 4) * 128;
  const int col0 = (blockIdx.x & 15) * 128;

  f32x4 acc[4][4];
#pragma unroll
  for (int i = 0; i < 4; ++i)
#pragma unroll
    for (int j = 0; j < 4; ++j) acc[i][j] = (f32x4){0.f, 0.f, 0.f, 0.f};

  // chunk c (16 B) -> logical (r = c>>2, k-quad = c&3); LDS image is linear.
  const int c0 = tid, c1 = tid + 256;
  const int r0 = c0 >> 2, kq0 = (c0 & 3) * 8;
  const int r1 = c1 >> 2, kq1 = (c1 & 3) * 8;
  unsigned short* lb0 = (unsigned short*)((char*)nullptr);  // placate nothing
  const int lds0 = (wv * 64) * 8;          // elements; + implicit lane*16 B
  const int lds1 = (256 + wv * 64) * 8;

  const int fr = lane & 15, fq = (lane >> 4) * 8;

  for (int k0 = 0; k0 < IN_DIM; k0 += 32) {
    dma16(xh + (row0 + r0) * IN_DIM + k0 + kq0, sAh + lds0);
    dma16(xh + (row0 + r1) * IN_DIM + k0 + kq1, sAh + lds1);
    dma16(xl + (row0 + r0) * IN_DIM + k0 + kq0, sAl + lds0);
    dma16(xl + (row0 + r1) * IN_DIM + k0 + kq1, sAl + lds1);
    dma16(wh + (size_t)(col0 + r0) * IN_DIM + k0 + kq0, sBh + lds0);
    dma16(wh + (size_t)(col0 + r1) * IN_DIM + k0 + kq1, sBh + lds1);
    dma16(wl + (size_t)(col0 + r0) * IN_DIM + k0 + kq0, sBl + lds0);
    dma16(wl + (size_t)(col0 + r1) * IN_DIM + k0 + kq1, sBl + lds1);
    __syncthreads();

    short8 ah[4], al[4], bh[4], bl[4];
#pragma unroll
    for (int t = 0; t < 4; ++t) {
      ah[t] = *(const short8*)(sAh + (wm * 64 + t * 16 + fr) * 32 + fq);
      al[t] = *(const short8*)(sAl + (wm * 64 + t * 16 + fr) * 32 + fq);
      bh[t] = *(const short8*)(sBh + (wn * 64 + t * 16 + fr) * 32 + fq);
      bl[t] = *(const short8*)(sBl + (wn * 64 + t * 16 + fr) * 32 + fq);
    }
#pragma unroll
    for (int mt = 0; mt < 4; ++mt)
#pragma unroll
      for (int nt = 0; nt < 4; ++nt) {
        acc[mt][nt] = __builtin_amdgcn_mfma_f32_16x16x32_bf16(ah[mt], bh[nt], acc[mt][nt], 0, 0, 0);
        acc[mt][nt] = __builtin_amdgcn_mfma_f32_16x16x32_bf16(ah[mt], bl[nt], acc[mt][nt], 0, 0, 0);
        acc[mt][nt] = __builtin_amdgcn_mfma_f32_16x16x32_bf16(al[mt], bh[nt], acc[mt][nt], 0, 0, 0);
      }
    __syncthreads();
  }

  // epilogue: C/D layout col=lane&15, row=(lane>>4)*4+reg  [m89-verified]
  const int ccol = lane & 15, crow4 = (lane >> 4) * 4;
#pragma unroll
  for (int nt = 0; nt < 4; ++nt) {
    const int col = col0 + wn * 64 + nt * 16 + ccol;
    const float bias = be[col];
#pragma unroll
    for (int mt = 0; mt < 4; ++mt) {
      const size_t rb = row0 + wm * 64 + mt * 16 + crow4;
#pragma unroll
      for (int r = 0; r < 4; ++r)
        z[(rb + r) * HID + col] = acc[mt][nt][r] + bias;
    }
  }
}

// ---------------------------------------------------------------------------
// K3: per-row exact-rank threshold + sparsify + decode (fused).
// Also finds the 51st value; rows with gap < MARGIN are flagged for exact
// fp32 recomputation (bf16x3 error ~1e-6 could flip near-tied selections).
// ---------------------------------------------------------------------------
__global__ __launch_bounds__(256) void topk_decode_kernel(
    float* __restrict__ z, const float* __restrict__ WdT,
    const float* __restrict__ bd, float* __restrict__ recon,
    int* __restrict__ flagCount, int* __restrict__ flagList)
{
  __shared__ float2 s_pair[4][64];
  const int w = threadIdx.x >> 6;
  const int lane = threadIdx.x & 63;
  const int row = blockIdx.x * 4 + w;
  float* zr = z + (size_t)row * HID;

  float4 v4[8];
  float v[32];
  unsigned u[32];
#pragma unroll
  for (int j2 = 0; j2 < 8; ++j2) {
    v4[j2] = *(const float4*)(zr + j2 * 256 + lane * 4);
    v[j2 * 4 + 0] = v4[j2].x;
    v[j2 * 4 + 1] = v4[j2].y;
    v[j2 * 4 + 2] = v4[j2].z;
    v[j2 * 4 + 3] = v4[j2].w;
  }
#pragma unroll
  for (int j = 0; j < 32; ++j) u[j] = f2code(v[j]);

  // rank-50 code
  unsigned lo = 0u, hi = 0xFFFFFFFFu;
  while (hi - lo > 1u) {
    const unsigned mid = lo + ((hi - lo) >> 1);
    int c = 0;
#pragma unroll
    for (int j = 0; j < 32; ++j) c += (u[j] >= mid) ? 1 : 0;
#pragma unroll
    for (int s = 32; s > 0; s >>= 1) c += __shfl_xor(c, s, 64);
    if (c >= TOPK) lo = mid; else hi = mid;
  }
  // rank-51 code (in [0, lo])
  unsigned lo2 = 0u, hi2 = lo + 1u;
  while (hi2 - lo2 > 1u) {
    const unsigned mid = lo2 + ((hi2 - lo2) >> 1);
    int c = 0;
#pragma unroll
    for (int j = 0; j < 32; ++j) c += (u[j] >= mid) ? 1 : 0;
#pragma unroll
    for (int s = 32; s > 0; s >>= 1) c += __shfl_xor(c, s, 64);
    if (c >= TOPK + 1) lo2 = mid; else hi2 = mid;
  }
  if (lane == 0 && (code2f(lo) - code2f(lo2)) < MARGIN) {
    const int idx = atomicAdd(flagCount, 1);
    flagList[idx] = row;
  }

  // sparsify in place
#pragma unroll
  for (int j2 = 0; j2 < 8; ++j2) {
    float4 o;
    o.x = (u[j2 * 4 + 0] >= lo) ? v4[j2].x : 0.0f;
    o.y = (u[j2 * 4 + 1] >= lo) ? v4[j2].y : 0.0f;
    o.z = (u[j2 * 4 + 2] >= lo) ? v4[j2].z : 0.0f;
    o.w = (u[j2 * 4 + 3] >= lo) ? v4[j2].w : 0.0f;
    *(float4*)(zr + j2 * 256 + lane * 4) = o;
  }

  // ballot-compact survivors
  s_pair[w][lane] = make_float2(0.0f, __int_as_float(0));
  int base = 0;
#pragma unroll
  for (int j = 0; j < 32; ++j) {
    const bool pass = (u[j] >= lo);
    const unsigned long long mask = __ballot(pass);
    if (pass) {
      const int pos = base + __popcll(mask & ((1ull << lane) - 1ull));
      if (pos < 64) {
        const int h = (j >> 2) * 256 + lane * 4 + (j & 3);
        s_pair[w][pos] = make_float2(v[j], __int_as_float(h));
      }
    }
    base += __popcll(mask);
  }
  const int cnt = (base < 64) ? base : 64;

  float acc[8];
  {
    const float4 b0 = *(const float4*)(bd + lane * 8);
    const float4 b1 = *(const float4*)(bd + lane * 8 + 4);
    acc[0] = b0.x; acc[1] = b0.y; acc[2] = b0.z; acc[3] = b0.w;
    acc[4] = b1.x; acc[5] = b1.y; acc[6] = b1.z; acc[7] = b1.w;
  }
  for (int i = 0; i < cnt; ++i) {
    const float2 p = s_pair[w][i];
    const float zv = p.x;
    const int h = __float_as_int(p.y);
    const float* wr = WdT + (size_t)h * IN_DIM + lane * 8;
    const float4 w0 = *(const float4*)wr;
    const float4 w1 = *(const float4*)(wr + 4);
    acc[0] += zv * w0.x; acc[1] += zv * w0.y;
    acc[2] += zv * w0.z; acc[3] += zv * w0.w;
    acc[4] += zv * w1.x; acc[5] += zv * w1.y;
    acc[6] += zv * w1.z; acc[7] += zv * w1.w;
  }

  float* rr = recon + (size_t)row * IN_DIM + lane * 8;
  float4 o0, o1;
  o0.x = acc[0]; o0.y = acc[1]; o0.z = acc[2]; o0.w = acc[3];
  o1.x = acc[4]; o1.y = acc[5]; o1.z = acc[6]; o1.w = acc[7];
  *(float4*)(rr) = o0;
  *(float4*)(rr + 4) = o1;
}

// ---------------------------------------------------------------------------
// K4: exact fixup for flagged rows — recompute z with sequential ascending
// fp32 FMA (the R1 semantics that matched the np reference), redo selection,
// rewrite z_sparse row and recon row. One wave (64-thread block) per row.
// ---------------------------------------------------------------------------
__global__ __launch_bounds__(64) void fixup_kernel(
    const float* __restrict__ x, const float* __restrict__ We,
    const float* __restrict__ be, const float* __restrict__ bd,
    const float* __restrict__ pb, const float* __restrict__ WdT,
    const int* __restrict__ flagCount, const int* __restrict__ flagList,
    float* __restrict__ z, float* __restrict__ recon)
{
  __shared__ float sxc[IN_DIM];
  __shared__ float2 spair[64];
  const int lane = threadIdx.x;
  const int nflag = *flagCount;

  for (int fi = blockIdx.x; fi < nflag; fi += gridDim.x) {
    const int row = flagList[fi];
#pragma unroll
    for (int t = 0; t < 8; ++t) {
      const int k = lane + t * 64;
      sxc[k] = x[(size_t)row * IN_DIM + k] - (bd[k] + pb[k]);
    }
    __syncthreads();

    float v[32];
    unsigned u[32];
#pragma unroll
    for (int j = 0; j < 32; ++j) {
      const int f = lane + 64 * j;
      const float* wr = We + (size_t)f * IN_DIM;
      float a = 0.f;
      for (int k4 = 0; k4 < IN_DIM; k4 += 4) {
        const float4 w4 = *(const float4*)(wr + k4);
        a = fmaf(sxc[k4 + 0], w4.x, a);
        a = fmaf(sxc[k4 + 1], w4.y, a);
        a = fmaf(sxc[k4 + 2], w4.z, a);
        a = fmaf(sxc[k4 + 3], w4.w, a);
      }
      v[j] = a + be[f];
      u[j] = f2code(v[j]);
    }

    unsigned lo = 0u, hi = 0xFFFFFFFFu;
    while (hi - lo > 1u) {
      const unsigned mid = lo + ((hi - lo) >> 1);
      int c = 0;
#pragma unroll
      for (int j = 0; j < 32; ++j) c += (u[j] >= mid) ? 1 : 0;
#pragma unroll
      for (int s = 32; s > 0; s >>= 1) c += __shfl_xor(c, s, 64);
      if (c >= TOPK) lo = mid; else hi = mid;
    }

    // rewrite z_sparse row
#pragma unroll
    for (int j = 0; j < 32; ++j)
      z[(size_t)row * HID + lane + 64 * j] = (u[j] >= lo) ? v[j] : 0.0f;

    // compact + recon
    spair[lane] = make_float2(0.0f, __int_as_float(0));
    __syncthreads();
    int base = 0;
#pragma unroll
    for (int j = 0; j < 32; ++j) {
      const bool pass = (u[j] >= lo);
      const unsigned long long mask = __ballot(pass);
      if (pass) {
        const int pos = base + __popcll(mask & ((1ull << lane) - 1ull));
        if (pos < 64) spair[pos] = make_float2(v[j], __int_as_float(lane + 64 * j));
      }
      base += __popcll(mask);
    }
    __syncthreads();
    const int cnt = (base < 64) ? base : 64;

    float acc[8];
    {
      const float4 b0 = *(const float4*)(bd + lane * 8);
      const float4 b1 = *(const float4*)(bd + lane * 8 + 4);
      acc[0] = b0.x; acc[1] = b0.y; acc[2] = b0.z; acc[3] = b0.w;
      acc[4] = b1.x; acc[5] = b1.y; acc[6] = b1.z; acc[7] = b1.w;
    }
    for (int i = 0; i < cnt; ++i) {
      const float2 p = spair[i];
      const float* wr = WdT + (size_t)__float_as_int(p.y) * IN_DIM + lane * 8;
      const float4 w0 = *(const float4*)wr;
      const float4 w1 = *(const float4*)(wr + 4);
      acc[0] += p.x * w0.x; acc[1] += p.x * w0.y;
      acc[2] += p.x * w0.z; acc[3] += p.x * w0.w;
      acc[4] += p.x * w1.x; acc[5] += p.x * w1.y;
      acc[6] += p.x * w1.z; acc[7] += p.x * w1.w;
    }
    float* rr = recon + (size_t)row * IN_DIM + lane * 8;
    *(float4*)(rr) = make_float4(acc[0], acc[1], acc[2], acc[3]);
    *(float4*)(rr + 4) = make_float4(acc[4], acc[5], acc[6], acc[7]);
    __syncthreads();
  }
}

// ---------------------------------------------------------------------------
extern "C" void kernel_launch(void* const* d_in, const int* in_sizes, int n_in,
                              void* d_out, int out_size, void* d_ws, size_t ws_size,
                              hipStream_t stream)
{
  const float* x  = (const float*)d_in[0];
  const float* We = (const float*)d_in[1];
  const float* be = (const float*)d_in[2];
  const float* Wd = (const float*)d_in[3];
  const float* bd = (const float*)d_in[4];
  const float* pb = (const float*)d_in[5];

  const int M = in_sizes[0] / IN_DIM;   // 65536

  float* recon = (float*)d_out;                        // M x 512
  float* zs    = (float*)d_out + (size_t)M * IN_DIM;   // M x 2048 (z -> z_sparse)
  // xcHi/xcLo live in the recon region (dead until topk_decode writes it)
  unsigned short* xcHi = (unsigned short*)recon;                    // M*512 u16
  unsigned short* xcLo = xcHi + (size_t)M * IN_DIM;                 // M*512 u16

  char* ws = (char*)d_ws;
  float* WdT           = (float*)ws;                    // 4 MB
  unsigned short* WeHi = (unsigned short*)(ws + (4 << 20));   // 2 MB
  unsigned short* WeLo = (unsigned short*)(ws + (6 << 20));   // 2 MB
  int* flagCount       = (int*)(ws + (8 << 20));
  int* flagList        = flagCount + 16;

  hipMemsetAsync(flagCount, 0, 64, stream);
  transpose_wdec_kernel<<<1024, 256, 0, stream>>>(Wd, WdT);
  split_we_kernel<<<(HID * IN_DIM / 4) / 256, 256, 0, stream>>>(We, WeHi, WeLo);
  split_x_kernel<<<(M * (IN_DIM / 4)) / 256, 256, 0, stream>>>(x, bd, pb, xcHi, xcLo);
  enc_gemm_mfma_kernel<<<(M / 128) * (HID / 128), 256, 0, stream>>>(
      xcHi, xcLo, WeHi, WeLo, be, zs);
  topk_decode_kernel<<<M / 4, 256, 0, stream>>>(zs, WdT, bd, recon, flagCount, flagList);
  fixup_kernel<<<2048, 64, 0, stream>>>(x, We, be, bd, pb, WdT,
                                        flagCount, flagList, zs, recon);
}